// Round 8
// baseline (95.678 us; speedup 1.0000x reference)
//
#include <hip/hip_runtime.h>

// Problem constants (fixed by the reference)
#define NB    8
#define NPTS  4096
#define KNN   16

// r^2 exactly as the reference: RADIUS = 5.0/480 in f64, squared in f64,
// rounded to f32 by weak promotion in `d2 < radius*radius`.
#define R2F ((float)((5.0 / 480.0) * (5.0 / 480.0)))

// ---------------------------------------------------------------------------
// K_all: ONE kernel, brute-force ball query + MLP. R7 lesson: grid-wide
// sync (cooperative or manual spin) hangs/no-ops under this harness -> the
// spatial-hash producer/consumer structure is unusable in one kernel. But
// brute force is CHEAP: 134M pair tests x ~7 VALU ~= 11us device-wide, and
// it kills the k_bucket dispatch, the global handoff, the poison-cold
// dependent loads, and the sort (ballot scan emits first-16 ascending).
// Block = 1024 thr = 64 queries x 16 waves; grid 512; 2 blocks/CU.
//   stage: 4096 batch points (x, y, sq) -> LDS SoA (48KB). sq = x*x+y*y
//          (contract off) = rn(rn(x^2)+rn(y^2)), exactly ref's chain.
//   scan:  wave q handles queries 4q..4q+3; lanes sweep 64 candidates per
//          chunk, 64 chunks, j ascending. pass = (sqn+sq_j)-(tt+tt) < R2F,
//          tt = fmaf(yn, yj, xn*xj)  [bit-exact ref chain, verified R0-R4].
//          Ordered append: ballot + popc(mask below lane) -> slot; first-16
//          semantics by construction; self-pad slots >= cnt.
//   ph3:   wave q gathers neighbor slot q -> embT[2q][p], embT[2q+1][p]
//          (exact fp32 sub). embT/hsT OVERLAY the dead cand arrays.
//   ph4:   wave q: hidden units 8q..+8; k-ascending fmaf chain (ref order);
//          relu -> hsT[u][p] (conflict-free [u][p] layout).
//   ph5:   wave q: outputs 4q..+4; u-ascending b2-seeded fmaf chain (ref
//          order); W2 rows via wave-uniform scalar loads.
// ---------------------------------------------------------------------------
__global__ __launch_bounds__(1024, 8) void k_all(
    const float4* __restrict__ xytp4, const float* __restrict__ W1,
    const float* __restrict__ b1, const float* __restrict__ W2,
    const float* __restrict__ b2, float* __restrict__ out) {
#pragma clang fp contract(off)
  // 48KB union: phase A = candX/candY/candSQ [4096] each;
  //             phase B = embT[32][64] (8KB) + hsT[128][64] (32KB).
  __shared__ __align__(16) char smem[48 * 1024];
  __shared__ unsigned short idxlsT[KNN][64];  // [slot][query], persists

  float* candX  = (float*)smem;               // [4096]
  float* candY  = (float*)(smem + 16384);     // [4096]
  float* candSQ = (float*)(smem + 32768);     // [4096]
  float(*embT)[64] = (float(*)[64])smem;          // 32 x 64
  float(*hsT)[64]  = (float(*)[64])(smem + 8192); // 128 x 64

  const int t = threadIdx.x;
  const int p = t & 63;                       // lane; also query id in ph3+
  const int q = t >> 6;                       // wave id 0..15, uniform
  const int pbase = blockIdx.x * 64;          // global query base
  const int bb = pbase & ~4095;               // batch point base (global)
  const int lqbase = pbase & 4095;            // batch-local query base

  // ---- stage: whole batch (x, y, sq) -> LDS SoA, coalesced ----
#pragma unroll
  for (int r = 0; r < 4; ++r) {
    int i = t + 1024 * r;
    float4 P = xytp4[bb + i];
    float x = P.y, y = P.z;
    candX[i] = x; candY[i] = y;
    candSQ[i] = x * x + y * y;                // rn(rn(x^2)+rn(y^2)), as ref
  }
  __syncthreads();

  // query coords for ph3 (read BEFORE the overlay kills cand arrays)
  const float rqx = candX[lqbase + p], rqy = candY[lqbase + p];

  // ---- scan: wave q, queries 4q..4q+3, all 4096 candidates, j asc ----
  {
    const int q0 = q * 4;                     // block-local query base
    float qxv[4], qyv[4], qsv[4];
#pragma unroll
    for (int g = 0; g < 4; ++g) {             // uniform-address broadcast
      qxv[g] = candX[lqbase + q0 + g];
      qyv[g] = candY[lqbase + q0 + g];
      qsv[g] = candSQ[lqbase + q0 + g];
    }
    int cnt[4] = {0, 0, 0, 0};
    const unsigned long long below = (1ull << p) - 1;
#pragma unroll 4
    for (int ch = 0; ch < 64; ++ch) {
      int j = ch * 64 + p;
      float cx_ = candX[j], cy_ = candY[j], cs_ = candSQ[j];
#pragma unroll
      for (int g = 0; g < 4; ++g) {
        float tt = fmaf(qyv[g], cy_, qxv[g] * cx_);  // ref contracted dot
        float d = (qsv[g] + cs_) - (tt + tt);
        bool pass = d < R2F;
        unsigned long long mask = __ballot(pass);
        if (mask) {                           // uniform: scalar branch
          int slot = cnt[g] + __popcll(mask & below);
          if (pass && slot < KNN)
            idxlsT[slot][q0 + g] = (unsigned short)j;
          cnt[g] += __popcll(mask);
        }
      }
    }
    // self-pad remaining slots (every query passes itself, cnt >= 1)
#pragma unroll
    for (int g = 0; g < 4; ++g) {
      if (p >= cnt[g] && p < KNN)
        idxlsT[p][q0 + g] = (unsigned short)(lqbase + q0 + g);
    }
  }
  __syncthreads();                            // cand arrays dead after here

  // ---- ph3: gather + emb (wave q handles slot q of every query) ----
  {
    int m = idxlsT[q][p];                     // q uniform
    float4 M = xytp4[bb + m];                 // L2-resident gather
    embT[2 * q][p] = rqx - M.y;               // exact fp32 sub, as ref
    embT[2 * q + 1][p] = rqy - M.z;           // bank p%32: conflict-free
  }
  __syncthreads();

  // ---- ph4: wave q -> hidden units 8q..+8; k-ascending, j inner ----
  {
    const int u0 = __builtin_amdgcn_readfirstlane(q) * 8;
    float h[8];
#pragma unroll
    for (int j = 0; j < 8; ++j) h[j] = b1[u0 + j];
#pragma unroll
    for (int k = 0; k < 32; ++k) {            // ascending k, as ref
      float ek = embT[k][p];                  // conflict-free b32
      const float* __restrict__ w0 = W1 + k * 128 + u0;  // uniform
#pragma unroll
      for (int j = 0; j < 8; ++j) h[j] = fmaf(ek, w0[j], h[j]);
    }
#pragma unroll
    for (int j = 0; j < 8; ++j)
      hsT[u0 + j][p] = fmaxf(h[j], 0.f);      // conflict-free b32 writes
  }
  __syncthreads();

  // ---- ph5: wave q -> outputs 4q..+4; u-ascending from b2 seed ----
  {
    const int o0 = __builtin_amdgcn_readfirstlane(q) * 4;
    float acc[4];
#pragma unroll
    for (int j = 0; j < 4; ++j) acc[j] = b2[o0 + j];
#pragma unroll 8
    for (int g = 0; g < 64; ++g) {            // u = 2g, 2g+1, ascending
      float h0 = hsT[2 * g][p];               // ds_read2-able pair,
      float h1 = hsT[2 * g + 1][p];           // conflict-free
      const float* __restrict__ w0 = W2 + (2 * g) * 64 + o0;   // uniform
#pragma unroll
      for (int j = 0; j < 4; ++j) acc[j] = fmaf(h0, w0[j], acc[j]);
#pragma unroll
      for (int j = 0; j < 4; ++j) acc[j] = fmaf(h1, w0[64 + j], acc[j]);
    }
    *(float4*)(out + (size_t)(pbase + p) * 64 + o0) =
        make_float4(acc[0], acc[1], acc[2], acc[3]);
  }
}

extern "C" void kernel_launch(void* const* d_in, const int* in_sizes, int n_in,
                              void* d_out, int out_size, void* d_ws, size_t ws_size,
                              hipStream_t stream) {
  const float4* xytp4 = (const float4*)d_in[0];  // [8,4096] (x=ch1, y=ch2)
  const float* W1 = (const float*)d_in[1];
  const float* b1 = (const float*)d_in[2];
  const float* W2 = (const float*)d_in[3];
  const float* b2 = (const float*)d_in[4];
  float* out = (float*)d_out;
  (void)d_ws; (void)ws_size;                  // workspace unused now

  hipLaunchKernelGGL(k_all, dim3(512), dim3(1024), 0, stream, xytp4, W1, b1,
                     W2, b2, out);
}

// Round 9
// 86.254 us; speedup vs baseline: 1.1093x; 1.1093x over previous
//
#include <hip/hip_runtime.h>

// Problem constants (fixed by the reference)
#define NB    8
#define NPTS  4096
#define KNN   16
#define CG    16          // coarse cells per axis; cell = 0.0625
#define NCC   (CG * CG)   // 256 cells per batch
#define PCAP  24          // passer cap per query (verified never hit, R4/R6)

// r^2 exactly as the reference: RADIUS = 5.0/480 in f64, squared in f64,
// rounded to f32 by weak promotion in `d2 < radius*radius`.
#define R2F ((float)((5.0 / 480.0) * (5.0 / 480.0)))
// Window half-width for cell pruning: must exceed max true pass distance
// sqrt(R2F + 5e-7) ~= 0.010441. 0.011 gives 5.6e-4 margin (>> any fp
// rounding in the window math). 2*0.011 < cell 0.0625 -> <= 2 cells/axis.
#define WIN 0.011f

// ---------------------------------------------------------------------------
// K_all: ONE kernel. R8 counters: k_all 40.7us, VALUBusy 69% -> brute-force
// scan (134M pair tests x ~8 VALU ~= 28us) dominates; MLP floor is 5.1us.
// Fix: BLOCK-LOCAL spatial pruning (no cross-block handoff -> no grid sync,
// which R7 proved fatal). Each block builds a 16x16-cell CSR of its batch's
// 4096 points in LDS (counts -> wave-0 prefix -> scatter, ~1us; redundant
// across blocks but trivially cheap). Query window <= 2x2 cells ~= 30
// candidates vs 4096: ~64x fewer tests. CSR order is scrambled (atomic
// scatter) -> collect passers (cap 24), insertion-sort ascending, first-16,
// self-pad: exactly the R4-verified selection semantics.
// All fp chains byte-identical to the R8-verified kernel (absmax 0.0):
//   sq = x*x + y*y (contract off); tt = fmaf(yn, cy, xn*cx);
//   d = (sqn + cs) - (tt + tt); pass = d < R2F; emb = exact f32 subs;
//   ph4 k-ascending, ph5 u-ascending b2-seeded fmaf chains.
// Block = 1024 thr = 64 queries x 16 waves; grid 512; 2 blocks/CU
// (LDS 63.3KB static; embT/hsT overlay the dead CSR region).
// ---------------------------------------------------------------------------
__global__ __launch_bounds__(1024, 8) void k_all(
    const float4* __restrict__ xytp4, const float* __restrict__ W1,
    const float* __restrict__ b1, const float* __restrict__ W2,
    const float* __restrict__ b2, float* __restrict__ out) {
#pragma clang fp contract(off)
  // Overlay region: phase A = CSR (x,y,sq f32[4096] + idx u16[4096]) 56KB;
  //                 phase B = embT[32][64] 8KB + hsT[128][64] 32KB.
  __shared__ __align__(16) char smem[57344];
  __shared__ int offs[NCC + 1];               // CSR starts (exclusive scan)
  __shared__ int cellcnt[NCC];                // counts, then scatter cursor
  __shared__ unsigned short plist[64 * PCAP]; // per-query passers (scrambled)
  __shared__ int pcnt[64];
  __shared__ unsigned short idxlsT[KNN][64];  // [slot][query], sorted

  float* csrX = (float*)smem;                       // [4096]
  float* csrY = (float*)(smem + 16384);             // [4096]
  float* csrSQ = (float*)(smem + 32768);            // [4096]
  unsigned short* csrIdx = (unsigned short*)(smem + 49152);  // [4096]
  float(*embT)[64] = (float(*)[64])smem;            // 32 x 64
  float(*hsT)[64] = (float(*)[64])(smem + 8192);    // 128 x 64

  const int t = threadIdx.x;
  const int p = t & 63;                       // lane
  const int q = t >> 6;                       // wave id 0..15, uniform
  const int pbase = blockIdx.x * 64;          // global query base
  const int bb = pbase & ~4095;               // batch point base (global)
  const int lqbase = pbase & 4095;            // batch-local query base

  // ---- build 1: load batch points into registers, count cells ----
  float4 Preg[4];
  int cellreg[4];
#pragma unroll
  for (int r = 0; r < 4; ++r) Preg[r] = xytp4[bb + t + 1024 * r];
  if (t < NCC) cellcnt[t] = 0;
  __syncthreads();
#pragma unroll
  for (int r = 0; r < 4; ++r) {
    int cx = min(CG - 1, max(0, (int)(Preg[r].y * (float)CG)));
    int cy = min(CG - 1, max(0, (int)(Preg[r].z * (float)CG)));
    cellreg[r] = cy * CG + cx;
    atomicAdd(&cellcnt[cellreg[r]], 1);
  }
  __syncthreads();

  // ---- build 2: wave 0 exclusive-scans 256 counts (4 cells/lane) ----
  if (q == 0) {
    int b4 = p * 4;
    int s0 = cellcnt[b4], s1 = cellcnt[b4 + 1], s2 = cellcnt[b4 + 2],
        s3 = cellcnt[b4 + 3];
    int tot = s0 + s1 + s2 + s3;
    int inc = tot;
#pragma unroll
    for (int d = 1; d < 64; d <<= 1) {
      int up = __shfl_up(inc, d);
      if (p >= d) inc += up;
    }
    int ex = inc - tot;
    offs[b4] = ex; offs[b4 + 1] = ex + s0;
    offs[b4 + 2] = ex + s0 + s1; offs[b4 + 3] = ex + s0 + s1 + s2;
    if (p == 63) offs[NCC] = inc;
    cellcnt[b4] = ex; cellcnt[b4 + 1] = ex + s0;        // -> cursors
    cellcnt[b4 + 2] = ex + s0 + s1; cellcnt[b4 + 3] = ex + s0 + s1 + s2;
  }
  __syncthreads();

  // ---- build 3: scatter (x, y, sq, idx) into CSR (order scrambled) ----
#pragma unroll
  for (int r = 0; r < 4; ++r) {
    float x = Preg[r].y, y = Preg[r].z;
    int pos = atomicAdd(&cellcnt[cellreg[r]], 1);
    csrX[pos] = x; csrY[pos] = y;
    csrSQ[pos] = x * x + y * y;               // rn(rn(x^2)+rn(y^2)), as ref
    csrIdx[pos] = (unsigned short)(t + 1024 * r);
  }
  __syncthreads();

  // ---- scan: wave q, queries 4q..4q+3; <=2x2 cell window each ----
  {
    const int q0 = q * 4;
    const unsigned long long below = (1ull << p) - 1;
#pragma unroll
    for (int g = 0; g < 4; ++g) {
      int lq = q0 + g;
      float4 P = xytp4[pbase + lq];           // uniform addr -> broadcast
      float xn = P.y, yn = P.z;
      float sqn = xn * xn + yn * yn;          // ref sq chain
      int cxlo = max(0, (int)((xn - WIN) * (float)CG));
      int cxhi = min(CG - 1, (int)((xn + WIN) * (float)CG));
      int cylo = max(0, (int)((yn - WIN) * (float)CG));
      int cyhi = min(CG - 1, (int)((yn + WIN) * (float)CG));
      int cnt = 0;
      for (int cy_ = cylo; cy_ <= cyhi; ++cy_)
        for (int cx_ = cxlo; cx_ <= cxhi; ++cx_) {
          int cell = cy_ * CG + cx_;
          int st = offs[cell], en = offs[cell + 1];
          for (int base = st; base < en; base += 64) {
            int e = base + p;
            bool act = e < en;
            int ee = act ? e : st;            // clamp to a valid address
            float cx2 = csrX[ee], cy2 = csrY[ee], cs2 = csrSQ[ee];
            float tt = fmaf(yn, cy2, xn * cx2);   // ref contracted dot
            float d = (sqn + cs2) - (tt + tt);
            bool pass = act && (d < R2F);
            unsigned long long mask = __ballot(pass);
            if (pass) {
              int slot = cnt + __popcll(mask & below);
              if (slot < PCAP) plist[lq * PCAP + slot] = csrIdx[ee];
            }
            cnt += __popcll(mask);
          }
        }
      if (p == 0) pcnt[lq] = cnt;
    }
  }
  __syncthreads();

  // ---- sort: t<64 sorts its passers ascending, first-16, self-pad ----
  if (t < 64) {
    int c = min(pcnt[t], PCAP);
    unsigned short* cand = &plist[t * PCAP];
    for (int i = 1; i < c; ++i) {             // insertion sort (c ~ 1-3)
      unsigned short key = cand[i];
      int j = i - 1;
      while (j >= 0 && cand[j] > key) { cand[j + 1] = cand[j]; --j; }
      cand[j + 1] = key;
    }
    if (c > KNN) c = KNN;
    unsigned short selfI = (unsigned short)(lqbase + t);
    for (int k = 0; k < KNN; ++k)
      idxlsT[k][t] = (k < c) ? cand[k] : selfI;
  }
  __syncthreads();                            // CSR dead after this point

  // ---- ph3: gather + emb (wave q handles slot q of every query) ----
  {
    float4 Pq = xytp4[pbase + p];             // query p's raw coords
    int m = idxlsT[q][p];                     // q uniform
    float4 M = xytp4[bb + m];                 // L2-resident gather
    embT[2 * q][p] = Pq.y - M.y;              // exact fp32 sub, as ref
    embT[2 * q + 1][p] = Pq.z - M.z;          // bank p%32: conflict-free
  }
  __syncthreads();

  // ---- ph4: wave q -> hidden units 8q..+8; k-ascending, j inner ----
  {
    const int u0 = __builtin_amdgcn_readfirstlane(q) * 8;
    float h[8];
#pragma unroll
    for (int j = 0; j < 8; ++j) h[j] = b1[u0 + j];
#pragma unroll
    for (int k = 0; k < 32; ++k) {            // ascending k, as ref
      float ek = embT[k][p];                  // conflict-free b32
      const float* __restrict__ w0 = W1 + k * 128 + u0;  // uniform
#pragma unroll
      for (int j = 0; j < 8; ++j) h[j] = fmaf(ek, w0[j], h[j]);
    }
#pragma unroll
    for (int j = 0; j < 8; ++j)
      hsT[u0 + j][p] = fmaxf(h[j], 0.f);      // conflict-free b32 writes
  }
  __syncthreads();

  // ---- ph5: wave q -> outputs 4q..+4; u-ascending from b2 seed ----
  {
    const int o0 = __builtin_amdgcn_readfirstlane(q) * 4;
    float acc[4];
#pragma unroll
    for (int j = 0; j < 4; ++j) acc[j] = b2[o0 + j];
#pragma unroll 8
    for (int g = 0; g < 64; ++g) {            // u = 2g, 2g+1, ascending
      float h0 = hsT[2 * g][p];               // ds_read2-able pair,
      float h1 = hsT[2 * g + 1][p];           // conflict-free
      const float* __restrict__ w0 = W2 + (2 * g) * 64 + o0;   // uniform
#pragma unroll
      for (int j = 0; j < 4; ++j) acc[j] = fmaf(h0, w0[j], acc[j]);
#pragma unroll
      for (int j = 0; j < 4; ++j) acc[j] = fmaf(h1, w0[64 + j], acc[j]);
    }
    *(float4*)(out + (size_t)(pbase + p) * 64 + o0) =
        make_float4(acc[0], acc[1], acc[2], acc[3]);
  }
}

extern "C" void kernel_launch(void* const* d_in, const int* in_sizes, int n_in,
                              void* d_out, int out_size, void* d_ws, size_t ws_size,
                              hipStream_t stream) {
  const float4* xytp4 = (const float4*)d_in[0];  // [8,4096] (x=ch1, y=ch2)
  const float* W1 = (const float*)d_in[1];
  const float* b1 = (const float*)d_in[2];
  const float* W2 = (const float*)d_in[3];
  const float* b2 = (const float*)d_in[4];
  float* out = (float*)d_out;
  (void)d_ws; (void)ws_size;                  // workspace unused

  hipLaunchKernelGGL(k_all, dim3(512), dim3(1024), 0, stream, xytp4, W1, b1,
                     W2, b2, out);
}